// Round 19
// baseline (182.079 us; speedup 1.0000x reference)
//
#include <hip/hip_runtime.h>

#define N_NODES 100000
#define OUT_CH  128
#define N_EDGES 625000
#define NB_SCAN 98
#define ROWD 68   // LDS row: 64 data dwords (128 bf16) + 4 pad

typedef short short8 __attribute__((ext_vector_type(8)));
typedef float f32x4  __attribute__((ext_vector_type(4)));
typedef float f32x2  __attribute__((ext_vector_type(2)));
typedef unsigned u32x4 __attribute__((ext_vector_type(4)));

__device__ inline short f32_bf16(float f) {
    union { float f; unsigned u; } c{f};
    unsigned r = 0x7FFFu + ((c.u >> 16) & 1u);
    return (short)((c.u + r) >> 16);
}
__device__ inline unsigned pack_bf16x2(float lo, float hi) {
    return (unsigned)(unsigned short)f32_bf16(lo) |
           ((unsigned)(unsigned short)f32_bf16(hi) << 16);
}
__device__ inline float sp_fast(float x) {
    float e = __expf(-fabsf(x));
    return fmaxf(x, 0.f) + __logf(1.f + e);
}

// ---- fp8 e4m3 (OCP) helpers: HW cvt if available, manual fallback ----
#if defined(__has_builtin)
#if __has_builtin(__builtin_amdgcn_cvt_pk_f32_fp8) && __has_builtin(__builtin_amdgcn_cvt_pk_fp8_f32)
#define HWFP8 1
#endif
#endif
#ifndef HWFP8
#define HWFP8 0
#endif

__device__ inline unsigned f32_fp8_manual(float f) {
    union { float fl; unsigned u; } c{f};
    unsigned s = (c.u >> 31) << 7;
    float af = fabsf(f);
    if (!(af < 448.f)) return s | 0x7E;
    if (af < 0.015625f) {
        unsigned q = (unsigned)__float2int_rn(af * 512.f);
        return s | q;
    }
    unsigned u = c.u;
    u += 0x7FFFF + ((u >> 20) & 1);
    int e = (int)((u >> 23) & 255) - 127;
    if (e > 8) return s | 0x7E;
    return s | (((unsigned)(e + 7)) << 3) | ((u >> 20) & 7);
}
__device__ inline float fp8_f32_manual(unsigned b) {
    unsigned s = (b >> 7) & 1, e = (b >> 3) & 15, m = b & 7;
    if (e) { union { unsigned u; float f; } c{(s << 31) | ((e + 120) << 23) | (m << 20)}; return c.f; }
    float v = (float)m * 0.001953125f;
    return s ? -v : v;
}

template <bool HI>
__device__ inline f32x2 fp8x2_f32(unsigned v) {
#if HWFP8
    return __builtin_amdgcn_cvt_pk_f32_fp8((int)v, HI);
#else
    unsigned sh = HI ? 16 : 0;
    f32x2 r;
    r.x = fp8_f32_manual((v >> sh) & 0xff);
    r.y = fp8_f32_manual((v >> (sh + 8)) & 0xff);
    return r;
#endif
}
template <bool HI>
__device__ inline unsigned fp8_pack2(float a, float b, unsigned old) {
#if HWFP8
    return (unsigned)__builtin_amdgcn_cvt_pk_fp8_f32(a, b, (int)old, HI);
#else
    unsigned v = f32_fp8_manual(a) | (f32_fp8_manual(b) << 8);
    return HI ? ((old & 0x0000ffffu) | (v << 16)) : ((old & 0xffff0000u) | v);
#endif
}

// ---- fused prep: W fragments | emb->fp8(x64) | edge histogram ----
#define NBB 16
#define NBE 6250
#define NBH 2442
__global__ void prep_all(const float* __restrict__ lw, const float* __restrict__ sw,
                         short8* __restrict__ B, const float4* __restrict__ emb,
                         uint2* __restrict__ embf8, const int* __restrict__ ei,
                         int* __restrict__ counts, int use_fp8) {
    int bid = blockIdx.x, tid = threadIdx.x;
    if (bid < NBB) {
        int g = bid * 256 + tid;
        int lane = g & 63, nt = (g >> 6) & 15, ks = g >> 10;
        int c = nt * 16 + (lane & 15);
        int k = ks * 32 + (lane >> 4) * 8;
        const float* src = (c < OUT_CH) ? (lw + c * OUT_CH + k)
                                        : (sw + (c - OUT_CH) * OUT_CH + k);
        short8 o;
#pragma unroll
        for (int j = 0; j < 8; ++j) o[j] = f32_bf16(src[j]);
        B[(ks * 16 + nt) * 64 + lane] = o;
    } else if (bid < NBB + NBE) {
        if (!use_fp8) return;
        int i = (bid - NBB) * 256 + tid;
        float4 a = emb[2 * i], b = emb[2 * i + 1];
        unsigned lo = fp8_pack2<false>(a.x * 64.f, a.y * 64.f, 0u);
        lo = fp8_pack2<true>(a.z * 64.f, a.w * 64.f, lo);
        unsigned hi = fp8_pack2<false>(b.x * 64.f, b.y * 64.f, 0u);
        hi = fp8_pack2<true>(b.z * 64.f, b.w * 64.f, hi);
        uint2 o; o.x = lo; o.y = hi;
        embf8[i] = o;
    } else {
        int e = (bid - NBB - NBE) * 256 + tid;
        if (e < N_EDGES) atomicAdd(&counts[ei[N_EDGES + e]], 1);
    }
}

// ---- scan1: wave-shuffle block scan; inits cursors ----
__global__ void scan1_k(const int* __restrict__ counts, int* __restrict__ offsets,
                        int* __restrict__ partials, int* __restrict__ cursors) {
    __shared__ int wsum[16];
    int tid = threadIdx.x, lane = tid & 63, wid = tid >> 6;
    int e = blockIdx.x * 1024 + tid;
    int v = (e < N_NODES) ? counts[e] : 0;
    int incl = v;
#pragma unroll
    for (int d = 1; d < 64; d <<= 1) {
        int t = __shfl_up(incl, d);
        if (lane >= d) incl += t;
    }
    if (lane == 63) wsum[wid] = incl;
    __syncthreads();
    if (wid == 0) {
        int w = (lane < 16) ? wsum[lane] : 0;
        int wi = w;
#pragma unroll
        for (int d = 1; d < 16; d <<= 1) {
            int t = __shfl_up(wi, d);
            if (lane >= d) wi += t;
        }
        if (lane < 16) wsum[lane] = wi - w;
        if (lane == 15) partials[blockIdx.x] = wi;
    }
    __syncthreads();
    int excl = incl - v + wsum[wid];
    if (e < N_NODES) { offsets[e] = excl; cursors[e] = excl; }
}

// ---- scan2: 98 partials, one wave, 2 elems/lane ----
__global__ void scan2_k(int* __restrict__ partials, int nb) {
    int lane = threadIdx.x;
    int i0 = 2 * lane, i1 = 2 * lane + 1;
    int v0 = (i0 < nb) ? partials[i0] : 0;
    int v1 = (i1 < nb) ? partials[i1] : 0;
    int s = v0 + v1;
    int incl = s;
#pragma unroll
    for (int d = 1; d < 64; d <<= 1) {
        int t = __shfl_up(incl, d);
        if (lane >= d) incl += t;
    }
    int excl = incl - s;
    if (i0 < nb) partials[i0] = excl;
    if (i1 < nb) partials[i1] = excl + v0;
}

// ---- reorder: one 16B edata record (s, norm, e, t) per sorted position ----
__global__ void reorder_k(const int* __restrict__ ei, const float* __restrict__ en,
                          const int* __restrict__ partials, int* __restrict__ cursors,
                          int4* __restrict__ edata, float nscale) {
    int e = blockIdx.x * blockDim.x + threadIdx.x;
    if (e >= N_EDGES) return;
    int t = ei[N_EDGES + e];
    int pos = partials[t >> 10] + atomicAdd(&cursors[t], 1);
    int4 d;
    d.x = ei[e];
    d.y = __float_as_int(en[e] * nscale);
    d.z = e;
    d.w = t;
    edata[pos] = d;
}

// ---- FUSED gather+GEMM v3: 512-thr/8-wave blocks, 8 nodes/block (linear
// order). Wave w gathers node bid*8+w, then computes tiles w (loc) and
// w+8 (std); A-rows 8-15 are zeroed. 4 blocks/CU for finer traffic mix. ----
__global__ __launch_bounds__(512) void enc_fp8_k(
        const unsigned short* __restrict__ embf8,
        const int* __restrict__ offsets, const int* __restrict__ partials,
        const int4* __restrict__ edata, const short8* __restrict__ B,
        const float* __restrict__ lb, const float* __restrict__ sb,
        float* __restrict__ out, unsigned* __restrict__ zf8) {
    __shared__ unsigned lds[16 * ROWD];
    int tid = threadIdx.x, wid = tid >> 6, lane = tid & 63;
    int node = __builtin_amdgcn_readfirstlane(blockIdx.x * 8 + wid);

    // zero pad row (wid+8): A-rows 8-15 read as 0
    for (int q = lane; q < ROWD; q += 64) lds[(wid + 8) * ROWD + q] = 0;

    int beg = offsets[node] + partials[node >> 10];
    int end = (node == N_NODES - 1) ? N_EDGES
              : offsets[node + 1] + partials[(node + 1) >> 10];
    float ax = 0.f, ay = 0.f;
    int j = beg;
    for (; j + 4 <= end; j += 4) {
        int4 p0 = edata[j], p1 = edata[j + 1], p2 = edata[j + 2], p3 = edata[j + 3];
        unsigned v0 = embf8[(size_t)p0.x * 64 + lane];
        unsigned v1 = embf8[(size_t)p1.x * 64 + lane];
        unsigned v2 = embf8[(size_t)p2.x * 64 + lane];
        unsigned v3 = embf8[(size_t)p3.x * 64 + lane];
        float n0f = __int_as_float(p0.y), n1f = __int_as_float(p1.y);
        float n2f = __int_as_float(p2.y), n3f = __int_as_float(p3.y);
        f32x2 d0 = fp8x2_f32<false>(v0), d1 = fp8x2_f32<false>(v1);
        f32x2 d2 = fp8x2_f32<false>(v2), d3 = fp8x2_f32<false>(v3);
        ax += d0.x * n0f + d1.x * n1f + d2.x * n2f + d3.x * n3f;
        ay += d0.y * n0f + d1.y * n1f + d2.y * n2f + d3.y * n3f;
    }
    for (; j < end; ++j) {
        int4 p = edata[j];
        float nm = __int_as_float(p.y);
        f32x2 d = fp8x2_f32<false>(embf8[(size_t)p.x * 64 + lane]);
        ax += d.x * nm; ay += d.y * nm;
    }
    lds[wid * ROWD + lane] = pack_bf16x2(ax, ay);
    __syncthreads();

    // GEMM phase: wave wid computes tile wid (loc) and wid+8 (std)
    int arow = lane & 15, hi4 = lane >> 4;
    f32x4 accL = (f32x4)(0.f), accS = (f32x4)(0.f);
#pragma unroll
    for (int ks = 0; ks < 4; ++ks) {
        short8 a = *(const short8*)&lds[arow * ROWD + ks * 16 + hi4 * 4];
        short8 wL = B[(ks * 16 + wid) * 64 + lane];
        short8 wS = B[(ks * 16 + wid + 8) * 64 + lane];
        accL = __builtin_amdgcn_mfma_f32_16x16x32_bf16(wL, a, accL, 0, 0, 0);
        accS = __builtin_amdgcn_mfma_f32_16x16x32_bf16(wS, a, accS, 0, 0, 0);
    }
    if (arow < 8) {
        int onode = blockIdx.x * 8 + arow;
        int c = wid * 16 + hi4 * 4;       // loc channel; std channel identical
        float4 bl = *(const float4*)(lb + c);
        float4 v;
        v.x = accL[0] + bl.x; v.y = accL[1] + bl.y;
        v.z = accL[2] + bl.z; v.w = accL[3] + bl.w;
        *(float4*)(out + (size_t)onode * OUT_CH + c) = v;
        unsigned zp = fp8_pack2<false>(v.x * 16.f, v.y * 16.f, 0u);
        zp = fp8_pack2<true>(v.z * 16.f, v.w * 16.f, zp);
        zf8[(size_t)onode * 32 + (c >> 2)] = zp;

        float4 bs = *(const float4*)(sb + c);
        float4 w;
        w.x = sp_fast(accS[0] + bs.x) + 1e-10f;
        w.y = sp_fast(accS[1] + bs.y) + 1e-10f;
        w.z = sp_fast(accS[2] + bs.z) + 1e-10f;
        w.w = sp_fast(accS[3] + bs.w) + 1e-10f;
        *(float4*)(out + (size_t)N_NODES * OUT_CH + (size_t)onode * OUT_CH + c) = w;
    }
}

// ---- fallback gather from f32 emb (writes bf16 ptrb) ----
__global__ void gather_f32_k(const float* __restrict__ emb,
                             const int* __restrict__ offsets,
                             const int* __restrict__ partials,
                             const int4* __restrict__ edata,
                             unsigned* __restrict__ ptrb) {
    int g = blockIdx.x * blockDim.x + threadIdx.x;
    int node = __builtin_amdgcn_readfirstlane(g >> 6);
    int lane = threadIdx.x & 63;
    if (node >= N_NODES) return;
    int beg = offsets[node] + partials[node >> 10];
    int end = (node == N_NODES - 1) ? N_EDGES
              : offsets[node + 1] + partials[(node + 1) >> 10];
    float ax = 0.f, ay = 0.f;
    const float2* base = (const float2*)emb;
    int j = beg;
    for (; j + 4 <= end; j += 4) {
        int4 p0 = edata[j], p1 = edata[j + 1], p2 = edata[j + 2], p3 = edata[j + 3];
        float2 v0 = base[(size_t)p0.x * 64 + lane];
        float2 v1 = base[(size_t)p1.x * 64 + lane];
        float2 v2 = base[(size_t)p2.x * 64 + lane];
        float2 v3 = base[(size_t)p3.x * 64 + lane];
        float n0f = __int_as_float(p0.y), n1f = __int_as_float(p1.y);
        float n2f = __int_as_float(p2.y), n3f = __int_as_float(p3.y);
        ax += v0.x * n0f + v1.x * n1f + v2.x * n2f + v3.x * n3f;
        ay += v0.y * n0f + v1.y * n1f + v2.y * n2f + v3.y * n3f;
    }
    for (; j < end; ++j) {
        int4 p = edata[j];
        float nm = __int_as_float(p.y);
        float2 v = base[(size_t)p.x * 64 + lane];
        ax += v.x * nm; ay += v.y * nm;
    }
    ptrb[(size_t)node * 64 + lane] = pack_bf16x2(ax, ay);
}

// ---- fallback loc/std GEMM (from ptrb) ----
__global__ __launch_bounds__(256) void gemm_k(const short* __restrict__ P,
                                              float* __restrict__ out,
                                              const short8* __restrict__ B,
                                              const float* __restrict__ lb,
                                              const float* __restrict__ sb) {
    int tid = threadIdx.x;
    int wave = tid >> 6, lane = tid & 63;
    int n0 = (blockIdx.x * 4 + wave) * 16;
    if (n0 >= N_NODES) return;

    float* loc  = out;
    float* stdo = out + (size_t)N_NODES * OUT_CH;

    int prow = n0 + (lane & 15);
    int kb = (lane >> 4) * 8;

    f32x4 acc[16];
#pragma unroll
    for (int i = 0; i < 16; ++i) acc[i] = (f32x4)(0.f);

#pragma unroll
    for (int ks = 0; ks < 4; ++ks) {
        short8 a = *(const short8*)(P + (size_t)prow * OUT_CH + ks * 32 + kb);
#pragma unroll
        for (int nt = 0; nt < 16; ++nt) {
            short8 w = B[(ks * 16 + nt) * 64 + lane];
            acc[nt] = __builtin_amdgcn_mfma_f32_16x16x32_bf16(w, a, acc[nt], 0, 0, 0);
        }
    }

    int node = n0 + (lane & 15);
    int ch4 = (lane >> 4) * 4;
    float* lrow = loc  + (size_t)node * OUT_CH;
    float* srow = stdo + (size_t)node * OUT_CH;

#pragma unroll
    for (int nt = 0; nt < 8; ++nt) {
        int c = nt * 16 + ch4;
        float4 b4 = *(const float4*)(lb + c);
        float4 v;
        v.x = acc[nt][0] + b4.x; v.y = acc[nt][1] + b4.y;
        v.z = acc[nt][2] + b4.z; v.w = acc[nt][3] + b4.w;
        *(float4*)(lrow + c) = v;
    }
#pragma unroll
    for (int nt = 8; nt < 16; ++nt) {
        int cc = nt * 16 + ch4 - OUT_CH;
        float4 b4 = *(const float4*)(sb + cc);
        float4 v;
        v.x = sp_fast(acc[nt][0] + b4.x) + 1e-10f;
        v.y = sp_fast(acc[nt][1] + b4.y) + 1e-10f;
        v.z = sp_fast(acc[nt][2] + b4.z) + 1e-10f;
        v.w = sp_fast(acc[nt][3] + b4.w) + 1e-10f;
        *(float4*)(srow + cc) = v;
    }
}

// ---- logits: 8 lanes/edge, u32x4 (16B) coalesced row reads, 3-step reduce ----
__global__ void logits_fp8_k(const u32x4* __restrict__ zf8,
                             const int4* __restrict__ edata,
                             float* __restrict__ lg) {
    int idx = blockIdx.x * blockDim.x + threadIdx.x;
    int p = idx >> 3, q = idx & 7;
    if (p >= N_EDGES) return;
    int4 md = edata[p];
    u32x4 a = zf8[(size_t)md.x * 8 + q];
    u32x4 b = zf8[(size_t)md.w * 8 + q];
    float d = 0.f;
#pragma unroll
    for (int k = 0; k < 4; ++k) {
        f32x2 al = fp8x2_f32<false>(a[k]), ah = fp8x2_f32<true>(a[k]);
        f32x2 bl = fp8x2_f32<false>(b[k]), bh = fp8x2_f32<true>(b[k]);
        d += al.x * bl.x + al.y * bl.y + ah.x * bh.x + ah.y * bh.y;
    }
#pragma unroll
    for (int m = 4; m >= 1; m >>= 1) d += __shfl_xor(d, m);
    if (q == 0) lg[md.z] = d * 0.00390625f;   // /256 (z scaled x16)
}

// ---- fallback: logits from f32 loc, original edge order ----
__global__ void logits_f32_k(const float* __restrict__ z, const int* __restrict__ ei,
                             float* __restrict__ lg) {
    int idx = blockIdx.x * blockDim.x + threadIdx.x;
    int e = idx >> 5, q = idx & 31;
    if (e >= N_EDGES) return;
    int s = ei[e], t = ei[N_EDGES + e];
    float4 a = *(const float4*)(z + (size_t)s * OUT_CH + q * 4);
    float4 b = *(const float4*)(z + (size_t)t * OUT_CH + q * 4);
    float d = a.x * b.x + a.y * b.y + a.z * b.z + a.w * b.w;
#pragma unroll
    for (int m = 16; m >= 1; m >>= 1) d += __shfl_xor(d, m);
    if (q == 0) lg[e] = d;
}

extern "C" void kernel_launch(void* const* d_in, const int* in_sizes, int n_in,
                              void* d_out, int out_size, void* d_ws, size_t ws_size,
                              hipStream_t stream) {
    const float* emb = (const float*)d_in[0];
    const int*   ei  = (const int*)d_in[1];
    const float* en  = (const float*)d_in[2];
    const float* lw  = (const float*)d_in[3];
    const float* lb  = (const float*)d_in[4];
    const float* sw  = (const float*)d_in[5];
    const float* sb  = (const float*)d_in[6];
    float* out = (float*)d_out;

    char* ws = (char*)d_ws;
    size_t o = 0;
    short8* B       = (short8*)(ws + o); o += 65536;
    int*    counts  = (int*)(ws + o);    o += 400128;
    int*    offsets = (int*)(ws + o);    o += 400128;
    int*    cursors = (int*)(ws + o);    o += 400128;
    int*    partials= (int*)(ws + o);    o += 1024;
    int4*   edata   = (int4*)(ws + o);   o += (size_t)N_EDGES * 16;
    unsigned* ptrb  = (unsigned*)(ws + o); o += (size_t)N_NODES * OUT_CH * 2; // fallback only

    unsigned* zf8   = (unsigned*)(ws + o);
    unsigned short* embf8 = (unsigned short*)(ws + o + (size_t)N_NODES * OUT_CH);
    size_t o_end = o + (size_t)N_NODES * OUT_CH * 2;   // zf8 + embf8
    int use_fp8 = (o_end <= ws_size) ? 1 : 0;

    hipMemsetAsync(counts, 0, N_NODES * sizeof(int), stream);

    prep_all<<<NBB + NBE + NBH, 256, 0, stream>>>(lw, sw, B, (const float4*)emb,
                                                  (uint2*)embf8, ei, counts, use_fp8);
    scan1_k<<<NB_SCAN, 1024, 0, stream>>>(counts, offsets, partials, cursors);
    scan2_k<<<1, 64, 0, stream>>>(partials, NB_SCAN);
    reorder_k<<<(N_EDGES + 255) / 256, 256, 0, stream>>>(
        ei, en, partials, cursors, edata, use_fp8 ? 0.015625f : 1.0f);
    float* lg = out + (size_t)2 * N_NODES * OUT_CH;
    if (use_fp8) {
        enc_fp8_k<<<N_NODES / 8, 512, 0, stream>>>(embf8, offsets, partials,
                                                   edata, B, lb, sb, out, zf8);
        logits_fp8_k<<<((size_t)N_EDGES * 8 + 255) / 256, 256, 0, stream>>>(
            (const u32x4*)zf8, edata, lg);
    } else {
        gather_f32_k<<<(N_NODES * 64 + 255) / 256, 256, 0, stream>>>(
            emb, offsets, partials, edata, ptrb);
        gemm_k<<<(N_NODES / 16 + 3) / 4, 256, 0, stream>>>((const short*)ptrb, out,
                                                           B, lb, sb);
        logits_f32_k<<<((size_t)N_EDGES * 32 + 255) / 256, 256, 0, stream>>>(out, ei, lg);
    }
}

// Round 20
// 173.475 us; speedup vs baseline: 1.0496x; 1.0496x over previous
//
#include <hip/hip_runtime.h>

#define N_NODES 100000
#define OUT_CH  128
#define N_EDGES 625000
#define NB_SCAN 98
#define ROWD 68   // LDS row: 64 data dwords (128 bf16) + 4 pad

typedef short short8 __attribute__((ext_vector_type(8)));
typedef float f32x4  __attribute__((ext_vector_type(4)));
typedef float f32x2  __attribute__((ext_vector_type(2)));
typedef unsigned u32x4 __attribute__((ext_vector_type(4)));

__device__ inline short f32_bf16(float f) {
    union { float f; unsigned u; } c{f};
    unsigned r = 0x7FFFu + ((c.u >> 16) & 1u);
    return (short)((c.u + r) >> 16);
}
__device__ inline unsigned pack_bf16x2(float lo, float hi) {
    return (unsigned)(unsigned short)f32_bf16(lo) |
           ((unsigned)(unsigned short)f32_bf16(hi) << 16);
}
__device__ inline float sp_fast(float x) {
    float e = __expf(-fabsf(x));
    return fmaxf(x, 0.f) + __logf(1.f + e);
}

// ---- fp8 e4m3 (OCP) helpers: HW cvt if available, manual fallback ----
#if defined(__has_builtin)
#if __has_builtin(__builtin_amdgcn_cvt_pk_f32_fp8) && __has_builtin(__builtin_amdgcn_cvt_pk_fp8_f32)
#define HWFP8 1
#endif
#endif
#ifndef HWFP8
#define HWFP8 0
#endif

__device__ inline unsigned f32_fp8_manual(float f) {
    union { float fl; unsigned u; } c{f};
    unsigned s = (c.u >> 31) << 7;
    float af = fabsf(f);
    if (!(af < 448.f)) return s | 0x7E;
    if (af < 0.015625f) {
        unsigned q = (unsigned)__float2int_rn(af * 512.f);
        return s | q;
    }
    unsigned u = c.u;
    u += 0x7FFFF + ((u >> 20) & 1);
    int e = (int)((u >> 23) & 255) - 127;
    if (e > 8) return s | 0x7E;
    return s | (((unsigned)(e + 7)) << 3) | ((u >> 20) & 7);
}
__device__ inline float fp8_f32_manual(unsigned b) {
    unsigned s = (b >> 7) & 1, e = (b >> 3) & 15, m = b & 7;
    if (e) { union { unsigned u; float f; } c{(s << 31) | ((e + 120) << 23) | (m << 20)}; return c.f; }
    float v = (float)m * 0.001953125f;
    return s ? -v : v;
}

template <bool HI>
__device__ inline f32x2 fp8x2_f32(unsigned v) {
#if HWFP8
    return __builtin_amdgcn_cvt_pk_f32_fp8((int)v, HI);
#else
    unsigned sh = HI ? 16 : 0;
    f32x2 r;
    r.x = fp8_f32_manual((v >> sh) & 0xff);
    r.y = fp8_f32_manual((v >> (sh + 8)) & 0xff);
    return r;
#endif
}
template <bool HI>
__device__ inline unsigned fp8_pack2(float a, float b, unsigned old) {
#if HWFP8
    return (unsigned)__builtin_amdgcn_cvt_pk_fp8_f32(a, b, (int)old, HI);
#else
    unsigned v = f32_fp8_manual(a) | (f32_fp8_manual(b) << 8);
    return HI ? ((old & 0x0000ffffu) | (v << 16)) : ((old & 0xffff0000u) | v);
#endif
}

// ---- fused prep: W fragments | emb->fp8(x64) | edge histogram ----
#define NBB 16
#define NBE 6250
#define NBH 2442
__global__ void prep_all(const float* __restrict__ lw, const float* __restrict__ sw,
                         short8* __restrict__ B, const float4* __restrict__ emb,
                         uint2* __restrict__ embf8, const int* __restrict__ ei,
                         int* __restrict__ counts, int use_fp8) {
    int bid = blockIdx.x, tid = threadIdx.x;
    if (bid < NBB) {
        int g = bid * 256 + tid;
        int lane = g & 63, nt = (g >> 6) & 15, ks = g >> 10;
        int c = nt * 16 + (lane & 15);
        int k = ks * 32 + (lane >> 4) * 8;
        const float* src = (c < OUT_CH) ? (lw + c * OUT_CH + k)
                                        : (sw + (c - OUT_CH) * OUT_CH + k);
        short8 o;
#pragma unroll
        for (int j = 0; j < 8; ++j) o[j] = f32_bf16(src[j]);
        B[(ks * 16 + nt) * 64 + lane] = o;
    } else if (bid < NBB + NBE) {
        if (!use_fp8) return;
        int i = (bid - NBB) * 256 + tid;
        float4 a = emb[2 * i], b = emb[2 * i + 1];
        unsigned lo = fp8_pack2<false>(a.x * 64.f, a.y * 64.f, 0u);
        lo = fp8_pack2<true>(a.z * 64.f, a.w * 64.f, lo);
        unsigned hi = fp8_pack2<false>(b.x * 64.f, b.y * 64.f, 0u);
        hi = fp8_pack2<true>(b.z * 64.f, b.w * 64.f, hi);
        uint2 o; o.x = lo; o.y = hi;
        embf8[i] = o;
    } else {
        int e = (bid - NBB - NBE) * 256 + tid;
        if (e < N_EDGES) atomicAdd(&counts[ei[N_EDGES + e]], 1);
    }
}

// ---- scan1: wave-shuffle block scan (block-local); inits cursors ----
__global__ void scan1_k(const int* __restrict__ counts, int* __restrict__ offsets,
                        int* __restrict__ partials, int* __restrict__ cursors) {
    __shared__ int wsum[16];
    int tid = threadIdx.x, lane = tid & 63, wid = tid >> 6;
    int e = blockIdx.x * 1024 + tid;
    int v = (e < N_NODES) ? counts[e] : 0;
    int incl = v;
#pragma unroll
    for (int d = 1; d < 64; d <<= 1) {
        int t = __shfl_up(incl, d);
        if (lane >= d) incl += t;
    }
    if (lane == 63) wsum[wid] = incl;
    __syncthreads();
    if (wid == 0) {
        int w = (lane < 16) ? wsum[lane] : 0;
        int wi = w;
#pragma unroll
        for (int d = 1; d < 16; d <<= 1) {
            int t = __shfl_up(wi, d);
            if (lane >= d) wi += t;
        }
        if (lane < 16) wsum[lane] = wi - w;
        if (lane == 15) partials[blockIdx.x] = wi;
    }
    __syncthreads();
    int excl = incl - v + wsum[wid];
    if (e < N_NODES) { offsets[e] = excl; cursors[e] = excl; }
}

// ---- scan2: 98 partials, one wave, 2 elems/lane ----
__global__ void scan2_k(int* __restrict__ partials, int nb) {
    int lane = threadIdx.x;
    int i0 = 2 * lane, i1 = 2 * lane + 1;
    int v0 = (i0 < nb) ? partials[i0] : 0;
    int v1 = (i1 < nb) ? partials[i1] : 0;
    int s = v0 + v1;
    int incl = s;
#pragma unroll
    for (int d = 1; d < 64; d <<= 1) {
        int t = __shfl_up(incl, d);
        if (lane >= d) incl += t;
    }
    int excl = incl - s;
    if (i0 < nb) partials[i0] = excl;
    if (i1 < nb) partials[i1] = excl + v0;
}

// ---- reorder: one 16B edata record (s, norm, e, t) per sorted position ----
__global__ void reorder_k(const int* __restrict__ ei, const float* __restrict__ en,
                          const int* __restrict__ partials, int* __restrict__ cursors,
                          int4* __restrict__ edata, float nscale) {
    int e = blockIdx.x * blockDim.x + threadIdx.x;
    if (e >= N_EDGES) return;
    int t = ei[N_EDGES + e];
    int pos = partials[t >> 10] + atomicAdd(&cursors[t], 1);
    int4 d;
    d.x = ei[e];
    d.y = __float_as_int(en[e] * nscale);
    d.z = e;
    d.w = t;
    edata[pos] = d;
}

// ---- FUSED gather+GEMM: 16 waves/block; wave w gathers node bid*16+w into
// LDS (full TLP: 100K gather waves), then computes one 16ch x 16node tile. ----
__global__ __launch_bounds__(1024) void enc_fp8_k(
        const unsigned short* __restrict__ embf8,
        const int* __restrict__ offsets, const int* __restrict__ partials,
        const int4* __restrict__ edata, const short8* __restrict__ B,
        const float* __restrict__ lb, const float* __restrict__ sb,
        float* __restrict__ out, unsigned* __restrict__ zf8) {
    __shared__ unsigned lds[16 * ROWD];
    int tid = threadIdx.x, wid = tid >> 6, lane = tid & 63;
    int node = __builtin_amdgcn_readfirstlane(blockIdx.x * 16 + wid);

    // gather phase: this wave's node, one row, scalar control loads
    int beg = offsets[node] + partials[node >> 10];
    int end = (node == N_NODES - 1) ? N_EDGES
              : offsets[node + 1] + partials[(node + 1) >> 10];
    float ax = 0.f, ay = 0.f;
    int j = beg;
    for (; j + 4 <= end; j += 4) {
        int4 p0 = edata[j], p1 = edata[j + 1], p2 = edata[j + 2], p3 = edata[j + 3];
        unsigned v0 = embf8[(size_t)p0.x * 64 + lane];
        unsigned v1 = embf8[(size_t)p1.x * 64 + lane];
        unsigned v2 = embf8[(size_t)p2.x * 64 + lane];
        unsigned v3 = embf8[(size_t)p3.x * 64 + lane];
        float n0f = __int_as_float(p0.y), n1f = __int_as_float(p1.y);
        float n2f = __int_as_float(p2.y), n3f = __int_as_float(p3.y);
        f32x2 d0 = fp8x2_f32<false>(v0), d1 = fp8x2_f32<false>(v1);
        f32x2 d2 = fp8x2_f32<false>(v2), d3 = fp8x2_f32<false>(v3);
        ax += d0.x * n0f + d1.x * n1f + d2.x * n2f + d3.x * n3f;
        ay += d0.y * n0f + d1.y * n1f + d2.y * n2f + d3.y * n3f;
    }
    for (; j < end; ++j) {
        int4 p = edata[j];
        float nm = __int_as_float(p.y);
        f32x2 d = fp8x2_f32<false>(embf8[(size_t)p.x * 64 + lane]);
        ax += d.x * nm; ay += d.y * nm;
    }
    lds[wid * ROWD + lane] = pack_bf16x2(ax, ay);
    __syncthreads();

    // GEMM phase: wave wid = output tile nt (16 channels x 16 nodes)
    int arow = lane & 15, hi = lane >> 4;
    f32x4 acc = (f32x4)(0.f);
#pragma unroll
    for (int ks = 0; ks < 4; ++ks) {
        short8 a = *(const short8*)&lds[arow * ROWD + ks * 16 + hi * 4];
        short8 w = B[(ks * 16 + wid) * 64 + lane];
        acc = __builtin_amdgcn_mfma_f32_16x16x32_bf16(w, a, acc, 0, 0, 0);
    }
    int onode = blockIdx.x * 16 + arow;   // C/D: col=lane&15 -> node
    int ch4 = hi * 4;                     // row=(lane>>4)*4+reg -> channel
    if (wid < 8) {
        int c = wid * 16 + ch4;
        float4 b4 = *(const float4*)(lb + c);
        float4 v;
        v.x = acc[0] + b4.x; v.y = acc[1] + b4.y;
        v.z = acc[2] + b4.z; v.w = acc[3] + b4.w;
        *(float4*)(out + (size_t)onode * OUT_CH + c) = v;
        unsigned zp = fp8_pack2<false>(v.x * 16.f, v.y * 16.f, 0u);
        zp = fp8_pack2<true>(v.z * 16.f, v.w * 16.f, zp);
        zf8[(size_t)onode * 32 + (c >> 2)] = zp;
    } else {
        int cc = (wid - 8) * 16 + ch4;
        float4 b4 = *(const float4*)(sb + cc);
        float4 v;
        v.x = sp_fast(acc[0] + b4.x) + 1e-10f;
        v.y = sp_fast(acc[1] + b4.y) + 1e-10f;
        v.z = sp_fast(acc[2] + b4.z) + 1e-10f;
        v.w = sp_fast(acc[3] + b4.w) + 1e-10f;
        *(float4*)(out + (size_t)N_NODES * OUT_CH + (size_t)onode * OUT_CH + cc) = v;
    }
}

// ---- fallback gather from f32 emb (writes bf16 ptrb) ----
__global__ void gather_f32_k(const float* __restrict__ emb,
                             const int* __restrict__ offsets,
                             const int* __restrict__ partials,
                             const int4* __restrict__ edata,
                             unsigned* __restrict__ ptrb) {
    int g = blockIdx.x * blockDim.x + threadIdx.x;
    int node = __builtin_amdgcn_readfirstlane(g >> 6);
    int lane = threadIdx.x & 63;
    if (node >= N_NODES) return;
    int beg = offsets[node] + partials[node >> 10];
    int end = (node == N_NODES - 1) ? N_EDGES
              : offsets[node + 1] + partials[(node + 1) >> 10];
    float ax = 0.f, ay = 0.f;
    const float2* base = (const float2*)emb;
    int j = beg;
    for (; j + 4 <= end; j += 4) {
        int4 p0 = edata[j], p1 = edata[j + 1], p2 = edata[j + 2], p3 = edata[j + 3];
        float2 v0 = base[(size_t)p0.x * 64 + lane];
        float2 v1 = base[(size_t)p1.x * 64 + lane];
        float2 v2 = base[(size_t)p2.x * 64 + lane];
        float2 v3 = base[(size_t)p3.x * 64 + lane];
        float n0f = __int_as_float(p0.y), n1f = __int_as_float(p1.y);
        float n2f = __int_as_float(p2.y), n3f = __int_as_float(p3.y);
        ax += v0.x * n0f + v1.x * n1f + v2.x * n2f + v3.x * n3f;
        ay += v0.y * n0f + v1.y * n1f + v2.y * n2f + v3.y * n3f;
    }
    for (; j < end; ++j) {
        int4 p = edata[j];
        float nm = __int_as_float(p.y);
        float2 v = base[(size_t)p.x * 64 + lane];
        ax += v.x * nm; ay += v.y * nm;
    }
    ptrb[(size_t)node * 64 + lane] = pack_bf16x2(ax, ay);
}

// ---- fallback loc/std GEMM (from ptrb) ----
__global__ __launch_bounds__(256) void gemm_k(const short* __restrict__ P,
                                              float* __restrict__ out,
                                              const short8* __restrict__ B,
                                              const float* __restrict__ lb,
                                              const float* __restrict__ sb) {
    int tid = threadIdx.x;
    int wave = tid >> 6, lane = tid & 63;
    int n0 = (blockIdx.x * 4 + wave) * 16;
    if (n0 >= N_NODES) return;

    float* loc  = out;
    float* stdo = out + (size_t)N_NODES * OUT_CH;

    int prow = n0 + (lane & 15);
    int kb = (lane >> 4) * 8;

    f32x4 acc[16];
#pragma unroll
    for (int i = 0; i < 16; ++i) acc[i] = (f32x4)(0.f);

#pragma unroll
    for (int ks = 0; ks < 4; ++ks) {
        short8 a = *(const short8*)(P + (size_t)prow * OUT_CH + ks * 32 + kb);
#pragma unroll
        for (int nt = 0; nt < 16; ++nt) {
            short8 w = B[(ks * 16 + nt) * 64 + lane];
            acc[nt] = __builtin_amdgcn_mfma_f32_16x16x32_bf16(w, a, acc[nt], 0, 0, 0);
        }
    }

    int node = n0 + (lane & 15);
    int ch4 = (lane >> 4) * 4;
    float* lrow = loc  + (size_t)node * OUT_CH;
    float* srow = stdo + (size_t)node * OUT_CH;

#pragma unroll
    for (int nt = 0; nt < 8; ++nt) {
        int c = nt * 16 + ch4;
        float4 b4 = *(const float4*)(lb + c);
        float4 v;
        v.x = acc[nt][0] + b4.x; v.y = acc[nt][1] + b4.y;
        v.z = acc[nt][2] + b4.z; v.w = acc[nt][3] + b4.w;
        *(float4*)(lrow + c) = v;
    }
#pragma unroll
    for (int nt = 8; nt < 16; ++nt) {
        int cc = nt * 16 + ch4 - OUT_CH;
        float4 b4 = *(const float4*)(sb + cc);
        float4 v;
        v.x = sp_fast(acc[nt][0] + b4.x) + 1e-10f;
        v.y = sp_fast(acc[nt][1] + b4.y) + 1e-10f;
        v.z = sp_fast(acc[nt][2] + b4.z) + 1e-10f;
        v.w = sp_fast(acc[nt][3] + b4.w) + 1e-10f;
        *(float4*)(srow + cc) = v;
    }
}

// ---- logits: 8 lanes/edge, u32x4 (16B) coalesced row reads, 3-step reduce ----
__global__ void logits_fp8_k(const u32x4* __restrict__ zf8,
                             const int4* __restrict__ edata,
                             float* __restrict__ lg) {
    int idx = blockIdx.x * blockDim.x + threadIdx.x;
    int p = idx >> 3, q = idx & 7;
    if (p >= N_EDGES) return;
    int4 md = edata[p];
    u32x4 a = zf8[(size_t)md.x * 8 + q];
    u32x4 b = zf8[(size_t)md.w * 8 + q];
    float d = 0.f;
#pragma unroll
    for (int k = 0; k < 4; ++k) {
        f32x2 al = fp8x2_f32<false>(a[k]), ah = fp8x2_f32<true>(a[k]);
        f32x2 bl = fp8x2_f32<false>(b[k]), bh = fp8x2_f32<true>(b[k]);
        d += al.x * bl.x + al.y * bl.y + ah.x * bh.x + ah.y * bh.y;
    }
#pragma unroll
    for (int m = 4; m >= 1; m >>= 1) d += __shfl_xor(d, m);
    if (q == 0) lg[md.z] = d * 0.00390625f;   // /256 (z scaled x16)
}

// ---- fallback: logits from f32 loc, original edge order ----
__global__ void logits_f32_k(const float* __restrict__ z, const int* __restrict__ ei,
                             float* __restrict__ lg) {
    int idx = blockIdx.x * blockDim.x + threadIdx.x;
    int e = idx >> 5, q = idx & 31;
    if (e >= N_EDGES) return;
    int s = ei[e], t = ei[N_EDGES + e];
    float4 a = *(const float4*)(z + (size_t)s * OUT_CH + q * 4);
    float4 b = *(const float4*)(z + (size_t)t * OUT_CH + q * 4);
    float d = a.x * b.x + a.y * b.y + a.z * b.z + a.w * b.w;
#pragma unroll
    for (int m = 16; m >= 1; m >>= 1) d += __shfl_xor(d, m);
    if (q == 0) lg[e] = d;
}

extern "C" void kernel_launch(void* const* d_in, const int* in_sizes, int n_in,
                              void* d_out, int out_size, void* d_ws, size_t ws_size,
                              hipStream_t stream) {
    const float* emb = (const float*)d_in[0];
    const int*   ei  = (const int*)d_in[1];
    const float* en  = (const float*)d_in[2];
    const float* lw  = (const float*)d_in[3];
    const float* lb  = (const float*)d_in[4];
    const float* sw  = (const float*)d_in[5];
    const float* sb  = (const float*)d_in[6];
    float* out = (float*)d_out;

    char* ws = (char*)d_ws;
    size_t o = 0;
    short8* B       = (short8*)(ws + o); o += 65536;
    int*    counts  = (int*)(ws + o);    o += 400128;
    int*    offsets = (int*)(ws + o);    o += 400128;
    int*    cursors = (int*)(ws + o);    o += 400128;
    int*    partials= (int*)(ws + o);    o += 1024;
    int4*   edata   = (int4*)(ws + o);   o += (size_t)N_EDGES * 16;
    unsigned* ptrb  = (unsigned*)(ws + o); o += (size_t)N_NODES * OUT_CH * 2; // fallback only

    unsigned* zf8   = (unsigned*)(ws + o);
    unsigned short* embf8 = (unsigned short*)(ws + o + (size_t)N_NODES * OUT_CH);
    size_t o_end = o + (size_t)N_NODES * OUT_CH * 2;   // zf8 + embf8
    int use_fp8 = (o_end <= ws_size) ? 1 : 0;

    hipMemsetAsync(counts, 0, N_NODES * sizeof(int), stream);

    prep_all<<<NBB + NBE + NBH, 256, 0, stream>>>(lw, sw, B, (const float4*)emb,
                                                  (uint2*)embf8, ei, counts, use_fp8);
    scan1_k<<<NB_SCAN, 1024, 0, stream>>>(counts, offsets, partials, cursors);
    scan2_k<<<1, 64, 0, stream>>>(partials, NB_SCAN);
    reorder_k<<<(N_EDGES + 255) / 256, 256, 0, stream>>>(
        ei, en, partials, cursors, edata, use_fp8 ? 0.015625f : 1.0f);
    float* lg = out + (size_t)2 * N_NODES * OUT_CH;
    if (use_fp8) {
        enc_fp8_k<<<N_NODES / 16, 1024, 0, stream>>>(embf8, offsets, partials,
                                                     edata, B, lb, sb, out, zf8);
        logits_fp8_k<<<((size_t)N_EDGES * 8 + 255) / 256, 256, 0, stream>>>(
            (const u32x4*)zf8, edata, lg);
    } else {
        gather_f32_k<<<(N_NODES * 64 + 255) / 256, 256, 0, stream>>>(
            emb, offsets, partials, edata, ptrb);
        gemm_k<<<(N_NODES / 16 + 3) / 4, 256, 0, stream>>>((const short*)ptrb, out,
                                                           B, lb, sb);
        logits_f32_k<<<((size_t)N_EDGES * 32 + 255) / 256, 256, 0, stream>>>(out, ei, lg);
    }
}